// Round 1
// baseline (338.762 us; speedup 1.0000x reference)
//
#include <hip/hip_runtime.h>
#include <stdint.h>

#define NUM_E 50000
#define EMBED_DIM 128
#define HID_DIM 200
#define BATCH 512
#define NN 50
#define HPAD 208   // 13*16 (x columns padded)
#define KPAD 224   // 7*32  (scores GEMM K padded)

typedef short s16x8 __attribute__((ext_vector_type(8)));
typedef float f32x4 __attribute__((ext_vector_type(4)));

__device__ inline unsigned short f2bf(float f) {
  union { float f; unsigned u; } v; v.f = f;
  unsigned r = v.u + 0x7FFF + ((v.u >> 16) & 1);
  return (unsigned short)(r >> 16);
}
__device__ inline float bf2f(unsigned short b) {
  union { unsigned u; float f; } v; v.u = ((unsigned)b) << 16;
  return v.f;
}

// ---------------------------------------------------------------------------
// Kernel A1: x = gather(embeddings, idx) @ Ws_w^T + Ws_b
// M=25600 (flat b,n), N=208 (H padded), K=128. MFMA 16x16x32 bf16.
// Also emits per-row sum of squares (for L2 normalize).
// ---------------------------------------------------------------------------
__global__ __launch_bounds__(256) void k_xgemm(
    const int* __restrict__ idx, const float* __restrict__ emb,
    const float* __restrict__ Ws_w, const float* __restrict__ Ws_b,
    unsigned short* __restrict__ x_ws, float* __restrict__ sumsq_ws)
{
  __shared__ unsigned short Al[64 * 40];   // 64 rows x 32 k, pad to 40
  __shared__ unsigned short Bl[208 * 40];  // 208 rows x 32 k, pad to 40
  const int tid = threadIdx.x;
  const int wave = tid >> 6, lane = tid & 63;
  const int q = lane >> 4, l15 = lane & 15;
  const int row0 = blockIdx.x * 64;

  f32x4 acc[13];
  for (int i = 0; i < 13; i++) acc[i] = (f32x4){0, 0, 0, 0};

  for (int kt = 0; kt < 4; ++kt) {
    const int k0 = kt * 32;
    // stage A: 64 rows x 32 cols (gather + fp32->bf16)
    {
      const int r = tid >> 2, q4 = tid & 3;
      const int erow = idx[row0 + r];
      const float* src = emb + (size_t)erow * EMBED_DIM + k0 + q4 * 8;
      float4 f0 = *(const float4*)(src);
      float4 f1 = *(const float4*)(src + 4);
      unsigned short tmp[8] __attribute__((aligned(16))) = {
        f2bf(f0.x), f2bf(f0.y), f2bf(f0.z), f2bf(f0.w),
        f2bf(f1.x), f2bf(f1.y), f2bf(f1.z), f2bf(f1.w)};
      *(uint4*)&Al[r * 40 + q4 * 8] = *(uint4*)tmp;
    }
    // stage B: Ws_w rows 0..207 x 32 cols (zero-pad rows >= 200)
    if (tid < 208) {
      unsigned short tmp[32] __attribute__((aligned(16)));
      if (tid < HID_DIM) {
        const float* src = Ws_w + (size_t)tid * EMBED_DIM + k0;
        for (int j = 0; j < 8; j++) {
          float4 f = *(const float4*)(src + j * 4);
          tmp[j*4+0] = f2bf(f.x); tmp[j*4+1] = f2bf(f.y);
          tmp[j*4+2] = f2bf(f.z); tmp[j*4+3] = f2bf(f.w);
        }
      } else {
        for (int j = 0; j < 32; j++) tmp[j] = 0;
      }
      for (int j = 0; j < 4; j++)
        *(uint4*)&Bl[tid * 40 + j * 8] = *(uint4*)&tmp[j * 8];
    }
    __syncthreads();
    s16x8 a = *(const s16x8*)&Al[(wave * 16 + l15) * 40 + q * 8];
    for (int ni = 0; ni < 13; ++ni) {
      s16x8 bfr = *(const s16x8*)&Bl[(ni * 16 + l15) * 40 + q * 8];
      acc[ni] = __builtin_amdgcn_mfma_f32_16x16x32_bf16(a, bfr, acc[ni], 0, 0, 0);
    }
    __syncthreads();
  }

  // epilogue: + Ws_b, per-row sumsq, store x as bf16
  float sq[4] = {0, 0, 0, 0};
  for (int ni = 0; ni < 13; ++ni) {
    const int col = ni * 16 + l15;
    const bool cv = col < HID_DIM;
    const float bias = cv ? Ws_b[col] : 0.f;
    for (int p = 0; p < 4; p++) {
      float v = acc[ni][p] + bias;
      if (cv) sq[p] += v * v;
      const int grow = row0 + wave * 16 + q * 4 + p;
      x_ws[(size_t)grow * HPAD + col] = f2bf(cv ? v : 0.f);
    }
  }
  for (int m = 1; m < 16; m <<= 1)
    for (int p = 0; p < 4; p++) sq[p] += __shfl_xor(sq[p], m, 64);
  if (l15 == 0)
    for (int p = 0; p < 4; p++)
      sumsq_ws[row0 + wave * 16 + q * 4 + p] = sq[p];
}

// ---------------------------------------------------------------------------
// Kernel A2: per-batch routing (3 iters) -> poses (bf16, K-padded), c dedup,
// p-softmax denominator D_b, exp(a) per history slot.
// ---------------------------------------------------------------------------
__global__ __launch_bounds__(256) void k_routing(
    const int* __restrict__ idx, const int* __restrict__ times,
    const unsigned short* __restrict__ x_ws, const float* __restrict__ sumsq_ws,
    unsigned short* __restrict__ poses_bf, float* __restrict__ expa_ws,
    float* __restrict__ D_ws)
{
  __shared__ float u[NN * 201];   // padded stride 201: conflict-free both axes
  __shared__ float cc[NN];
  __shared__ float bb[NN];
  __shared__ float vv[HID_DIM];
  __shared__ float nrm[NN];
  __shared__ int   sidx[NN];
  __shared__ float red[4];
  __shared__ float scaleS;
  const int tid = threadIdx.x;
  const int b = blockIdx.x;

  if (tid < NN) {
    nrm[tid] = fmaxf(sqrtf(sumsq_ws[b * NN + tid]), 1e-12f);
    sidx[tid] = idx[b * NN + tid];
    bb[tid] = 2.0f / (1.0f + (float)times[b * NN + tid]);
  }
  __syncthreads();
  for (int i = tid; i < NN * HID_DIM; i += 256) {
    const int n = i / HID_DIM, h = i - n * HID_DIM;
    u[n * 201 + h] = bf2f(x_ws[(size_t)(b * NN + n) * HPAD + h]) / nrm[n];
  }
  __syncthreads();

  for (int it = 0; it < 3; ++it) {
    // softmax(bb) * N  (wave 0)
    if (tid < 64) {
      float x = (tid < NN) ? bb[tid] : -1e30f;
      float m = x;
      for (int d = 1; d < 64; d <<= 1) m = fmaxf(m, __shfl_xor(m, d, 64));
      float e = (tid < NN) ? __expf(x - m) : 0.f;
      float s = e;
      for (int d = 1; d < 64; d <<= 1) s += __shfl_xor(s, d, 64);
      if (tid < NN) cc[tid] = e * (float)NN / s;
    }
    __syncthreads();
    // s_h = sum_n c_n u[n][h]
    float sh = 0.f;
    if (tid < HID_DIM)
      for (int n = 0; n < NN; n++) sh += cc[n] * u[n * 201 + tid];
    float sq = (tid < HID_DIM) ? sh * sh : 0.f;
    for (int d = 1; d < 64; d <<= 1) sq += __shfl_xor(sq, d, 64);
    if ((tid & 63) == 0) red[tid >> 6] = sq;
    __syncthreads();
    if (tid == 0) {
      const float t = red[0] + red[1] + red[2] + red[3];
      scaleS = t / (1.0f + t) / sqrtf(t + 1e-9f);
    }
    __syncthreads();
    if (tid < HID_DIM) vv[tid] = scaleS * sh;
    __syncthreads();
    if (it < 2) {
      if (tid < NN) {
        float dot = 0.f;
        for (int h = 0; h < HID_DIM; h++) dot += u[tid * 201 + h] * vv[h];
        bb[tid] += dot;
      }
      __syncthreads();
    }
  }
  // poses, bf16 zero-padded to KPAD
  if (tid < KPAD)
    poses_bf[(size_t)b * KPAD + tid] =
        (tid < HID_DIM) ? f2bf(vv[tid]) : (unsigned short)0;
  // dedup of idx within row; D_b = NUM_E + sum_unique (exp(a)-1)
  if (tid < 64) {
    float a = 0.f; int first = 1;
    const int my = (tid < NN) ? sidx[tid] : -1;
    if (tid < NN) {
      for (int n = 0; n < NN; n++)
        if (sidx[n] == my) { a += cc[n]; if (n < tid) first = 0; }
      expa_ws[b * NN + tid] = __expf(a);
    }
    float contrib = (tid < NN && first) ? (__expf(a) - 1.0f) : 0.f;
    for (int d = 1; d < 64; d <<= 1) contrib += __shfl_xor(contrib, d, 64);
    if (tid == 0) D_ws[b] = (float)NUM_E + contrib;
  }
}

// ---------------------------------------------------------------------------
// Kernel B: scores = poses @ mlp_w^T + mlp_b  (M=512, N=50000, K=224 padded)
// Writes fp32 scores into d_out; atomically accumulates S_b = sum exp(score).
// Tile 128x128, BK=32, 4 waves each 32 rows x 128 cols.
// ---------------------------------------------------------------------------
__global__ __launch_bounds__(256) void k_scores(
    const unsigned short* __restrict__ poses_bf, const float* __restrict__ mlp_w,
    const float* __restrict__ mlp_b, float* __restrict__ out,
    float* __restrict__ S_ws)
{
  __shared__ unsigned short Al[128 * 40];
  __shared__ unsigned short Bl[128 * 40];
  const int tid = threadIdx.x;
  const int wave = tid >> 6, lane = tid & 63;
  const int q = lane >> 4, l15 = lane & 15;
  const int n0 = blockIdx.x * 128;
  const int m0 = blockIdx.y * 128;

  f32x4 acc[2][8];
  for (int i = 0; i < 2; i++)
    for (int j = 0; j < 8; j++) acc[i][j] = (f32x4){0, 0, 0, 0};

  const int r = tid >> 1, half = tid & 1;
  for (int kt = 0; kt < 7; ++kt) {
    const int k0 = kt * 32;
    // stage A (poses, already bf16): row m0+r, 16 cols
    {
      const unsigned short* src = poses_bf + (size_t)(m0 + r) * KPAD + k0 + half * 16;
      uint4 u0 = *(const uint4*)src;
      uint4 u1 = *(const uint4*)(src + 8);
      *(uint4*)&Al[r * 40 + half * 16] = u0;
      *(uint4*)&Al[r * 40 + half * 16 + 8] = u1;
    }
    // stage B (mlp_w fp32 -> bf16, zero-pad k>=200 and rows>=NUM_E)
    {
      const int grow = n0 + r;
      const int cbase = k0 + half * 16;
      unsigned short tmp[16] __attribute__((aligned(16)));
      if (grow < NUM_E) {
        const float* src = mlp_w + (size_t)grow * HID_DIM + cbase;
        for (int j = 0; j < 4; j++) {
          const int c = cbase + j * 4;
          if (c + 3 < HID_DIM) {
            float4 f = *(const float4*)(src + j * 4);
            tmp[j*4+0] = f2bf(f.x); tmp[j*4+1] = f2bf(f.y);
            tmp[j*4+2] = f2bf(f.z); tmp[j*4+3] = f2bf(f.w);
          } else {
            tmp[j*4+0] = 0; tmp[j*4+1] = 0; tmp[j*4+2] = 0; tmp[j*4+3] = 0;
          }
        }
      } else {
        for (int j = 0; j < 16; j++) tmp[j] = 0;
      }
      *(uint4*)&Bl[r * 40 + half * 16]     = *(uint4*)&tmp[0];
      *(uint4*)&Bl[r * 40 + half * 16 + 8] = *(uint4*)&tmp[8];
    }
    __syncthreads();
    for (int mi = 0; mi < 2; ++mi) {
      s16x8 a = *(const s16x8*)&Al[(wave * 32 + mi * 16 + l15) * 40 + q * 8];
      for (int ni = 0; ni < 8; ++ni) {
        s16x8 bfr = *(const s16x8*)&Bl[(ni * 16 + l15) * 40 + q * 8];
        acc[mi][ni] = __builtin_amdgcn_mfma_f32_16x16x32_bf16(a, bfr, acc[mi][ni], 0, 0, 0);
      }
    }
    __syncthreads();
  }

  // epilogue: + mlp_b, store fp32 scores, accumulate exp-sums per row
  float rowsum[2][4] = {{0,0,0,0},{0,0,0,0}};
  for (int ni = 0; ni < 8; ++ni) {
    const int col = n0 + ni * 16 + l15;
    const bool cv = col < NUM_E;
    const float bias = cv ? mlp_b[col] : 0.f;
    for (int mi = 0; mi < 2; ++mi) {
      for (int p = 0; p < 4; p++) {
        const float v = acc[mi][ni][p] + bias;
        if (cv) {
          const int grow = m0 + wave * 32 + mi * 16 + q * 4 + p;
          out[(size_t)grow * NUM_E + col] = v;
          rowsum[mi][p] += __expf(v);
        }
      }
    }
  }
  for (int m = 1; m < 16; m <<= 1)
    for (int mi = 0; mi < 2; mi++)
      for (int p = 0; p < 4; p++)
        rowsum[mi][p] += __shfl_xor(rowsum[mi][p], m, 64);
  if (l15 == 0)
    for (int mi = 0; mi < 2; mi++)
      for (int p = 0; p < 4; p++) {
        const int grow = m0 + wave * 32 + mi * 16 + q * 4 + p;
        atomicAdd(&S_ws[grow], rowsum[mi][p]);
      }
}

// ---------------------------------------------------------------------------
// Kernel Bsave: snapshot scores at history positions (before in-place final)
// ---------------------------------------------------------------------------
__global__ __launch_bounds__(256) void k_histsave(
    const int* __restrict__ idx, const float* __restrict__ out,
    float* __restrict__ hist)
{
  const int t = blockIdx.x * 256 + threadIdx.x;
  if (t < BATCH * NN) {
    const int b = t / NN;
    const int j = idx[t];
    hist[t] = out[(size_t)b * NUM_E + j];
  }
}

// ---------------------------------------------------------------------------
// Kernel C: out = log(0.5/D_b + 0.5*exp(score)/S_b)  (in place, float4)
// ---------------------------------------------------------------------------
__global__ __launch_bounds__(256) void k_final(
    float* __restrict__ out, const float* __restrict__ D_ws,
    const float* __restrict__ S_ws)
{
  const int b = blockIdx.y;
  const int c4 = blockIdx.x * 256 + threadIdx.x;
  if (c4 < NUM_E / 4) {
    const float invD = 0.5f / D_ws[b];
    const float invS = 0.5f / S_ws[b];
    float4* p = (float4*)(out + (size_t)b * NUM_E) + c4;
    float4 v = *p;
    v.x = __logf(fmaf(__expf(v.x), invS, invD));
    v.y = __logf(fmaf(__expf(v.y), invS, invD));
    v.z = __logf(fmaf(__expf(v.z), invS, invD));
    v.w = __logf(fmaf(__expf(v.w), invS, invD));
    *p = v;
  }
}

// ---------------------------------------------------------------------------
// Kernel D: fixup history positions with true p = exp(a)/D_b
// (duplicate idx threads write identical aggregated values -> benign race)
// ---------------------------------------------------------------------------
__global__ __launch_bounds__(256) void k_fix(
    const int* __restrict__ idx, const float* __restrict__ expa,
    const float* __restrict__ hist, const float* __restrict__ D_ws,
    const float* __restrict__ S_ws, float* __restrict__ out)
{
  const int t = blockIdx.x * 256 + threadIdx.x;
  if (t < BATCH * NN) {
    const int b = t / NN;
    const int j = idx[t];
    const float val = __logf(0.5f * expa[t] / D_ws[b] +
                             0.5f * __expf(hist[t]) / S_ws[b]);
    out[(size_t)b * NUM_E + j] = val;
  }
}

extern "C" void kernel_launch(void* const* d_in, const int* in_sizes, int n_in,
                              void* d_out, int out_size, void* d_ws, size_t ws_size,
                              hipStream_t stream) {
  const int*   idx   = (const int*)d_in[0];
  const int*   times = (const int*)d_in[1];
  const float* emb   = (const float*)d_in[2];
  const float* Ws_w  = (const float*)d_in[3];
  const float* Ws_b  = (const float*)d_in[4];
  const float* mlp_w = (const float*)d_in[5];
  const float* mlp_b = (const float*)d_in[6];
  float* out = (float*)d_out;

  char* ws = (char*)d_ws;
  unsigned short* x_ws  = (unsigned short*)ws; ws += (size_t)BATCH * NN * HPAD * 2; // 10.65 MB
  float* sumsq          = (float*)ws;          ws += (size_t)BATCH * NN * 4;        // 102 KB
  unsigned short* poses = (unsigned short*)ws; ws += (size_t)BATCH * KPAD * 2;      // 229 KB
  float* expa           = (float*)ws;          ws += (size_t)BATCH * NN * 4;        // 102 KB
  float* D_ws           = (float*)ws;          ws += (size_t)BATCH * 4;
  float* S_ws           = (float*)ws;          ws += (size_t)BATCH * 4;
  float* hist           = (float*)ws;          ws += (size_t)BATCH * NN * 4;        // 102 KB

  hipMemsetAsync(S_ws, 0, BATCH * sizeof(float), stream);
  k_xgemm  <<<dim3(400),      256, 0, stream>>>(idx, emb, Ws_w, Ws_b, x_ws, sumsq);
  k_routing<<<dim3(BATCH),    256, 0, stream>>>(idx, times, x_ws, sumsq, poses, expa, D_ws);
  k_scores <<<dim3(391, 4),   256, 0, stream>>>(poses, mlp_w, mlp_b, out, S_ws);
  k_histsave<<<dim3(100),     256, 0, stream>>>(idx, out, hist);
  k_final  <<<dim3(49, BATCH),256, 0, stream>>>(out, D_ws, S_ws);
  k_fix    <<<dim3(100),      256, 0, stream>>>(idx, expa, hist, D_ws, S_ws, out);
}

// Round 2
// 327.525 us; speedup vs baseline: 1.0343x; 1.0343x over previous
//
#include <hip/hip_runtime.h>
#include <stdint.h>

#define NUM_E 50000
#define EMBED_DIM 128
#define HID_DIM 200
#define BATCH 512
#define NN 50
#define HPAD 208   // 13*16 (x columns padded)
#define KPAD 224   // 7*32  (scores GEMM K padded)
#define NKT 7      // K tiles of 32
#define NTT 3125   // N fragment tiles (50000/16)

typedef short s16x8 __attribute__((ext_vector_type(8)));
typedef float f32x4 __attribute__((ext_vector_type(4)));

__device__ inline unsigned short f2bf(float f) {
  union { float f; unsigned u; } v; v.f = f;
  unsigned r = v.u + 0x7FFF + ((v.u >> 16) & 1);
  return (unsigned short)(r >> 16);
}
__device__ inline float bf2f(unsigned short b) {
  union { unsigned u; float f; } v; v.u = ((unsigned)b) << 16;
  return v.f;
}

// ---------------------------------------------------------------------------
// Kernel A1: x = gather(embeddings, idx) @ Ws_w^T + Ws_b
// M=25600 (flat b,n), N=208 (H padded), K=128. MFMA 16x16x32 bf16.
// Also emits per-row sum of squares (for L2 normalize).
// ---------------------------------------------------------------------------
__global__ __launch_bounds__(256) void k_xgemm(
    const int* __restrict__ idx, const float* __restrict__ emb,
    const float* __restrict__ Ws_w, const float* __restrict__ Ws_b,
    unsigned short* __restrict__ x_ws, float* __restrict__ sumsq_ws)
{
  __shared__ unsigned short Al[64 * 40];   // 64 rows x 32 k, pad to 40
  __shared__ unsigned short Bl[208 * 40];  // 208 rows x 32 k, pad to 40
  const int tid = threadIdx.x;
  const int wave = tid >> 6, lane = tid & 63;
  const int q = lane >> 4, l15 = lane & 15;
  const int row0 = blockIdx.x * 64;

  f32x4 acc[13];
  for (int i = 0; i < 13; i++) acc[i] = (f32x4){0, 0, 0, 0};

  for (int kt = 0; kt < 4; ++kt) {
    const int k0 = kt * 32;
    // stage A: 64 rows x 32 cols (gather + fp32->bf16)
    {
      const int r = tid >> 2, q4 = tid & 3;
      const int erow = idx[row0 + r];
      const float* src = emb + (size_t)erow * EMBED_DIM + k0 + q4 * 8;
      float4 f0 = *(const float4*)(src);
      float4 f1 = *(const float4*)(src + 4);
      unsigned short tmp[8] __attribute__((aligned(16))) = {
        f2bf(f0.x), f2bf(f0.y), f2bf(f0.z), f2bf(f0.w),
        f2bf(f1.x), f2bf(f1.y), f2bf(f1.z), f2bf(f1.w)};
      *(uint4*)&Al[r * 40 + q4 * 8] = *(uint4*)tmp;
    }
    // stage B: Ws_w rows 0..207 x 32 cols (zero-pad rows >= 200)
    if (tid < 208) {
      unsigned short tmp[32] __attribute__((aligned(16)));
      if (tid < HID_DIM) {
        const float* src = Ws_w + (size_t)tid * EMBED_DIM + k0;
        for (int j = 0; j < 8; j++) {
          float4 f = *(const float4*)(src + j * 4);
          tmp[j*4+0] = f2bf(f.x); tmp[j*4+1] = f2bf(f.y);
          tmp[j*4+2] = f2bf(f.z); tmp[j*4+3] = f2bf(f.w);
        }
      } else {
        for (int j = 0; j < 32; j++) tmp[j] = 0;
      }
      for (int j = 0; j < 4; j++)
        *(uint4*)&Bl[tid * 40 + j * 8] = *(uint4*)&tmp[j * 8];
    }
    __syncthreads();
    s16x8 a = *(const s16x8*)&Al[(wave * 16 + l15) * 40 + q * 8];
    for (int ni = 0; ni < 13; ++ni) {
      s16x8 bfr = *(const s16x8*)&Bl[(ni * 16 + l15) * 40 + q * 8];
      acc[ni] = __builtin_amdgcn_mfma_f32_16x16x32_bf16(a, bfr, acc[ni], 0, 0, 0);
    }
    __syncthreads();
  }

  // epilogue: + Ws_b, per-row sumsq, store x as bf16
  float sq[4] = {0, 0, 0, 0};
  for (int ni = 0; ni < 13; ++ni) {
    const int col = ni * 16 + l15;
    const bool cv = col < HID_DIM;
    const float bias = cv ? Ws_b[col] : 0.f;
    for (int p = 0; p < 4; p++) {
      float v = acc[ni][p] + bias;
      if (cv) sq[p] += v * v;
      const int grow = row0 + wave * 16 + q * 4 + p;
      x_ws[(size_t)grow * HPAD + col] = f2bf(cv ? v : 0.f);
    }
  }
  for (int m = 1; m < 16; m <<= 1)
    for (int p = 0; p < 4; p++) sq[p] += __shfl_xor(sq[p], m, 64);
  if (l15 == 0)
    for (int p = 0; p < 4; p++)
      sumsq_ws[row0 + wave * 16 + q * 4 + p] = sq[p];
}

// ---------------------------------------------------------------------------
// Kernel A2: per-batch routing (3 iters). Emits:
//  - poses in MFMA A-fragment layout Ap[((mt*7+kt)*64 + q*16 + l15)*8 + j]
//  - exp(aggregated c) per history slot, and p-softmax denominator D_b
// ---------------------------------------------------------------------------
__global__ __launch_bounds__(256) void k_routing(
    const int* __restrict__ idx, const int* __restrict__ times,
    const unsigned short* __restrict__ x_ws, const float* __restrict__ sumsq_ws,
    unsigned short* __restrict__ Ap, float* __restrict__ expa_ws,
    float* __restrict__ D_ws)
{
  __shared__ float u[NN * 201];   // padded stride 201: conflict-free both axes
  __shared__ float cc[NN];
  __shared__ float bb[NN];
  __shared__ float vv[HID_DIM];
  __shared__ float nrm[NN];
  __shared__ int   sidx[NN];
  __shared__ float red[4];
  __shared__ float scaleS;
  const int tid = threadIdx.x;
  const int b = blockIdx.x;

  if (tid < NN) {
    nrm[tid] = fmaxf(sqrtf(sumsq_ws[b * NN + tid]), 1e-12f);
    sidx[tid] = idx[b * NN + tid];
    bb[tid] = 2.0f / (1.0f + (float)times[b * NN + tid]);
  }
  __syncthreads();
  for (int i = tid; i < NN * HID_DIM; i += 256) {
    const int n = i / HID_DIM, h = i - n * HID_DIM;
    u[n * 201 + h] = bf2f(x_ws[(size_t)(b * NN + n) * HPAD + h]) / nrm[n];
  }
  __syncthreads();

  for (int it = 0; it < 3; ++it) {
    // softmax(bb) * N  (wave 0)
    if (tid < 64) {
      float x = (tid < NN) ? bb[tid] : -1e30f;
      float m = x;
      for (int d = 1; d < 64; d <<= 1) m = fmaxf(m, __shfl_xor(m, d, 64));
      float e = (tid < NN) ? __expf(x - m) : 0.f;
      float s = e;
      for (int d = 1; d < 64; d <<= 1) s += __shfl_xor(s, d, 64);
      if (tid < NN) cc[tid] = e * (float)NN / s;
    }
    __syncthreads();
    // s_h = sum_n c_n u[n][h]
    float sh = 0.f;
    if (tid < HID_DIM)
      for (int n = 0; n < NN; n++) sh += cc[n] * u[n * 201 + tid];
    float sq = (tid < HID_DIM) ? sh * sh : 0.f;
    for (int d = 1; d < 64; d <<= 1) sq += __shfl_xor(sq, d, 64);
    if ((tid & 63) == 0) red[tid >> 6] = sq;
    __syncthreads();
    if (tid == 0) {
      const float t = red[0] + red[1] + red[2] + red[3];
      scaleS = t / (1.0f + t) / sqrtf(t + 1e-9f);
    }
    __syncthreads();
    if (tid < HID_DIM) vv[tid] = scaleS * sh;
    __syncthreads();
    if (it < 2) {
      if (tid < NN) {
        float dot = 0.f;
        for (int h = 0; h < HID_DIM; h++) dot += u[tid * 201 + h] * vv[h];
        bb[tid] += dot;
      }
      __syncthreads();
    }
  }
  // poses scattered into A-fragment layout (zero-padded to KPAD)
  if (tid < KPAD) {
    const float val = (tid < HID_DIM) ? vv[tid] : 0.f;
    const int kt = tid >> 5, rem = tid & 31, q = rem >> 3, j = rem & 7;
    const int mt = b >> 4, l15 = b & 15;
    Ap[(size_t)(((mt * NKT + kt) * 64) + q * 16 + l15) * 8 + j] = f2bf(val);
  }
  // dedup of idx within row; D_b = NUM_E + sum_unique (exp(a)-1)
  if (tid < 64) {
    float a = 0.f; int first = 1;
    const int my = (tid < NN) ? sidx[tid] : -1;
    if (tid < NN) {
      for (int n = 0; n < NN; n++)
        if (sidx[n] == my) { a += cc[n]; if (n < tid) first = 0; }
      expa_ws[b * NN + tid] = __expf(a);
    }
    float contrib = (tid < NN && first) ? (__expf(a) - 1.0f) : 0.f;
    for (int d = 1; d < 64; d <<= 1) contrib += __shfl_xor(contrib, d, 64);
    if (tid == 0) D_ws[b] = (float)NUM_E + contrib;
  }
}

// ---------------------------------------------------------------------------
// Kernel P: pre-pack mlp_w (fp32 [50000][200]) into bf16 MFMA B-fragment
// layout: Bp[((nt*7+kt)*64 + lane)*8 + j], lane = q*16 + l15,
//   col n = nt*16 + l15, k = kt*32 + q*8 + j  (zero for k >= 200)
// ---------------------------------------------------------------------------
__global__ __launch_bounds__(256) void k_pack(
    const float* __restrict__ mlp_w, unsigned short* __restrict__ Bp)
{
  const int t = blockIdx.x * 256 + threadIdx.x;
  if (t >= NTT * NKT * 64) return;
  const int lane = t & 63;
  const int f = t >> 6;
  const int kt = f % NKT;
  const int nt = f / NKT;
  const int n = nt * 16 + (lane & 15);
  const int kb = kt * 32 + (lane >> 4) * 8;
  unsigned short tmp[8] __attribute__((aligned(16)));
  if (kb < HID_DIM) {   // kb in {0..192 step 8}; kb+7 <= 199 always when kb<200
    const float* src = mlp_w + (size_t)n * HID_DIM + kb;
    float4 f0 = *(const float4*)(src);
    float4 f1 = *(const float4*)(src + 4);
    tmp[0] = f2bf(f0.x); tmp[1] = f2bf(f0.y); tmp[2] = f2bf(f0.z); tmp[3] = f2bf(f0.w);
    tmp[4] = f2bf(f1.x); tmp[5] = f2bf(f1.y); tmp[6] = f2bf(f1.z); tmp[7] = f2bf(f1.w);
  } else {
    for (int j = 0; j < 8; j++) tmp[j] = 0;
  }
  *(uint4*)&Bp[(size_t)t * 8] = *(uint4*)tmp;
}

// ---------------------------------------------------------------------------
// Kernel B: scores = poses @ mlp_w^T + mlp_b. Barrier-free, LDS-free.
// Block = 4 waves; wave tile 64M x 80N; block tile 256M x 80N.
// Grid (625, 2): 50000 = 625*80 exact, 512 = 2*256 exact, K = 7*32 exact.
// Stores bf16 scores; atomically accumulates S_b = sum exp(score).
// ---------------------------------------------------------------------------
__global__ __launch_bounds__(256) void k_scores(
    const unsigned short* __restrict__ Ap, const unsigned short* __restrict__ Bp,
    const float* __restrict__ mlp_b, unsigned short* __restrict__ scores_bf,
    float* __restrict__ S_ws)
{
  const int tid = threadIdx.x;
  const int wave = tid >> 6, lane = tid & 63;
  const int q = lane >> 4, l15 = lane & 15;
  const int m0 = blockIdx.y * 256 + wave * 64;
  const int mt0 = m0 >> 4;
  const int nt0 = blockIdx.x * 5;
  const int n0 = nt0 * 16;

  f32x4 acc[4][5];
  for (int i = 0; i < 4; i++)
    for (int j = 0; j < 5; j++) acc[i][j] = (f32x4){0, 0, 0, 0};

  #pragma unroll 2
  for (int kt = 0; kt < NKT; ++kt) {
    s16x8 a[4], bfr[5];
    #pragma unroll
    for (int mi = 0; mi < 4; ++mi)
      a[mi] = *(const s16x8*)&Ap[(size_t)(((mt0 + mi) * NKT + kt) * 64 + lane) * 8];
    #pragma unroll
    for (int ni = 0; ni < 5; ++ni)
      bfr[ni] = *(const s16x8*)&Bp[(size_t)(((nt0 + ni) * NKT + kt) * 64 + lane) * 8];
    #pragma unroll
    for (int ni = 0; ni < 5; ++ni)
      #pragma unroll
      for (int mi = 0; mi < 4; ++mi)
        acc[mi][ni] = __builtin_amdgcn_mfma_f32_16x16x32_bf16(a[mi], bfr[ni], acc[mi][ni], 0, 0, 0);
  }

  // epilogue: + mlp_b, bf16 store, per-row exp-sum
  float bias[5];
  #pragma unroll
  for (int ni = 0; ni < 5; ++ni) bias[ni] = mlp_b[n0 + ni * 16 + l15];

  float rowsum[4][4];
  for (int mi = 0; mi < 4; mi++)
    for (int p = 0; p < 4; p++) rowsum[mi][p] = 0.f;

  #pragma unroll
  for (int mi = 0; mi < 4; ++mi) {
    #pragma unroll
    for (int ni = 0; ni < 5; ++ni) {
      #pragma unroll
      for (int p = 0; p < 4; p++) {
        const float v = acc[mi][ni][p] + bias[ni];
        const int row = m0 + mi * 16 + q * 4 + p;
        const int col = n0 + ni * 16 + l15;
        scores_bf[(size_t)row * NUM_E + col] = f2bf(v);
        rowsum[mi][p] += __expf(v);
      }
    }
  }
  #pragma unroll
  for (int m = 1; m < 16; m <<= 1)
    for (int mi = 0; mi < 4; mi++)
      for (int p = 0; p < 4; p++)
        rowsum[mi][p] += __shfl_xor(rowsum[mi][p], m, 64);
  if (l15 == 0)
    for (int mi = 0; mi < 4; mi++)
      for (int p = 0; p < 4; p++)
        atomicAdd(&S_ws[m0 + mi * 16 + q * 4 + p], rowsum[mi][p]);
}

// ---------------------------------------------------------------------------
// Kernel C: out = log(0.5/D_b + 0.5*exp(score)/S_b), bf16 scores -> fp32 out
// ---------------------------------------------------------------------------
__global__ __launch_bounds__(256) void k_final(
    const unsigned short* __restrict__ scores_bf, const float* __restrict__ D_ws,
    const float* __restrict__ S_ws, float* __restrict__ out)
{
  const int b = blockIdx.y;
  const int c8 = blockIdx.x * 256 + threadIdx.x;
  if (c8 < NUM_E / 8) {
    const float invD = 0.5f / D_ws[b];
    const float invS = 0.5f / S_ws[b];
    const uint4 raw = *(const uint4*)(scores_bf + (size_t)b * NUM_E + c8 * 8);
    const unsigned w[4] = {raw.x, raw.y, raw.z, raw.w};
    float r[8];
    #pragma unroll
    for (int i = 0; i < 4; i++) {
      r[2*i]   = bf2f((unsigned short)(w[i] & 0xffff));
      r[2*i+1] = bf2f((unsigned short)(w[i] >> 16));
    }
    float4 o0, o1;
    o0.x = __logf(fmaf(__expf(r[0]), invS, invD));
    o0.y = __logf(fmaf(__expf(r[1]), invS, invD));
    o0.z = __logf(fmaf(__expf(r[2]), invS, invD));
    o0.w = __logf(fmaf(__expf(r[3]), invS, invD));
    o1.x = __logf(fmaf(__expf(r[4]), invS, invD));
    o1.y = __logf(fmaf(__expf(r[5]), invS, invD));
    o1.z = __logf(fmaf(__expf(r[6]), invS, invD));
    o1.w = __logf(fmaf(__expf(r[7]), invS, invD));
    float* dst = out + (size_t)b * NUM_E + c8 * 8;
    *(float4*)dst = o0;
    *(float4*)(dst + 4) = o1;
  }
}

// ---------------------------------------------------------------------------
// Kernel D: fixup history positions with true p = exp(a)/D_b
// (duplicate idx threads write identical aggregated values -> benign race)
// ---------------------------------------------------------------------------
__global__ __launch_bounds__(256) void k_fix(
    const int* __restrict__ idx, const float* __restrict__ expa,
    const unsigned short* __restrict__ scores_bf, const float* __restrict__ D_ws,
    const float* __restrict__ S_ws, float* __restrict__ out)
{
  const int t = blockIdx.x * 256 + threadIdx.x;
  if (t < BATCH * NN) {
    const int b = t / NN;
    const int j = idx[t];
    const float s = bf2f(scores_bf[(size_t)b * NUM_E + j]);
    out[(size_t)b * NUM_E + j] = __logf(0.5f * expa[t] / D_ws[b] +
                                        0.5f * __expf(s) / S_ws[b]);
  }
}

extern "C" void kernel_launch(void* const* d_in, const int* in_sizes, int n_in,
                              void* d_out, int out_size, void* d_ws, size_t ws_size,
                              hipStream_t stream) {
  const int*   idx   = (const int*)d_in[0];
  const int*   times = (const int*)d_in[1];
  const float* emb   = (const float*)d_in[2];
  const float* Ws_w  = (const float*)d_in[3];
  const float* Ws_b  = (const float*)d_in[4];
  const float* mlp_w = (const float*)d_in[5];
  const float* mlp_b = (const float*)d_in[6];
  float* out = (float*)d_out;

  char* ws = (char*)d_ws;
  unsigned short* scores_bf = (unsigned short*)ws; ws += (size_t)BATCH * NUM_E * 2;       // 51.2 MB
  unsigned short* Bp    = (unsigned short*)ws; ws += (size_t)NTT * NKT * 64 * 8 * 2;      // 22.4 MB
  unsigned short* x_ws  = (unsigned short*)ws; ws += (size_t)BATCH * NN * HPAD * 2;       // 10.65 MB
  unsigned short* Ap    = (unsigned short*)ws; ws += (size_t)32 * NKT * 64 * 8 * 2;       // 229 KB
  float* sumsq          = (float*)ws;          ws += (size_t)BATCH * NN * 4;              // 102 KB
  float* expa           = (float*)ws;          ws += (size_t)BATCH * NN * 4;              // 102 KB
  float* D_ws           = (float*)ws;          ws += (size_t)BATCH * 4;
  float* S_ws           = (float*)ws;          ws += (size_t)BATCH * 4;

  hipMemsetAsync(S_ws, 0, BATCH * sizeof(float), stream);
  k_pack   <<<dim3((NTT * NKT * 64 + 255) / 256), 256, 0, stream>>>(mlp_w, Bp);
  k_xgemm  <<<dim3(400),        256, 0, stream>>>(idx, emb, Ws_w, Ws_b, x_ws, sumsq);
  k_routing<<<dim3(BATCH),      256, 0, stream>>>(idx, times, x_ws, sumsq, Ap, expa, D_ws);
  k_scores <<<dim3(625, 2),     256, 0, stream>>>(Ap, Bp, mlp_b, scores_bf, S_ws);
  k_final  <<<dim3(25, BATCH),  256, 0, stream>>>(scores_bf, D_ws, S_ws, out);
  k_fix    <<<dim3(100),        256, 0, stream>>>(idx, expa, scores_bf, D_ws, S_ws, out);
}

// Round 3
// 268.105 us; speedup vs baseline: 1.2635x; 1.2216x over previous
//
#include <hip/hip_runtime.h>
#include <stdint.h>

#define NUM_E 50000
#define EMBED_DIM 128
#define HID_DIM 200
#define BATCH 512
#define NN 50
#define HPAD 208   // 13*16 (x columns padded)
#define KPAD 224   // 7*32  (scores GEMM K padded)
#define NKT 7      // K tiles of 32
#define NTT2 3136  // N fragment tiles padded: 3136*16 = 50176 = 196*256
#define NXB 196    // grid.x for scores GEMM

typedef short s16x8 __attribute__((ext_vector_type(8)));
typedef float f32x4 __attribute__((ext_vector_type(4)));

__device__ inline unsigned short f2bf(float f) {
  union { float f; unsigned u; } v; v.f = f;
  unsigned r = v.u + 0x7FFF + ((v.u >> 16) & 1);
  return (unsigned short)(r >> 16);
}
__device__ inline float bf2f(unsigned short b) {
  union { unsigned u; float f; } v; v.u = ((unsigned)b) << 16;
  return v.f;
}

// async global->LDS, 16B per lane; lds dst = uniform base + lane*16
__device__ __forceinline__ void gl_lds16(const unsigned short* g, unsigned short* l) {
  __builtin_amdgcn_global_load_lds(
      (const __attribute__((address_space(1))) unsigned int*)g,
      (__attribute__((address_space(3))) unsigned int*)l, 16, 0, 0);
}

// ---------------------------------------------------------------------------
// Kernel A1: x = gather(embeddings, idx) @ Ws_w^T + Ws_b   (unchanged)
// ---------------------------------------------------------------------------
__global__ __launch_bounds__(256) void k_xgemm(
    const int* __restrict__ idx, const float* __restrict__ emb,
    const float* __restrict__ Ws_w, const float* __restrict__ Ws_b,
    unsigned short* __restrict__ x_ws, float* __restrict__ sumsq_ws)
{
  __shared__ unsigned short Al[64 * 40];
  __shared__ unsigned short Bl[208 * 40];
  const int tid = threadIdx.x;
  const int wave = tid >> 6, lane = tid & 63;
  const int q = lane >> 4, l15 = lane & 15;
  const int row0 = blockIdx.x * 64;

  f32x4 acc[13];
  for (int i = 0; i < 13; i++) acc[i] = (f32x4){0, 0, 0, 0};

  for (int kt = 0; kt < 4; ++kt) {
    const int k0 = kt * 32;
    {
      const int r = tid >> 2, q4 = tid & 3;
      const int erow = idx[row0 + r];
      const float* src = emb + (size_t)erow * EMBED_DIM + k0 + q4 * 8;
      float4 f0 = *(const float4*)(src);
      float4 f1 = *(const float4*)(src + 4);
      unsigned short tmp[8] __attribute__((aligned(16))) = {
        f2bf(f0.x), f2bf(f0.y), f2bf(f0.z), f2bf(f0.w),
        f2bf(f1.x), f2bf(f1.y), f2bf(f1.z), f2bf(f1.w)};
      *(uint4*)&Al[r * 40 + q4 * 8] = *(uint4*)tmp;
    }
    if (tid < 208) {
      unsigned short tmp[32] __attribute__((aligned(16)));
      if (tid < HID_DIM) {
        const float* src = Ws_w + (size_t)tid * EMBED_DIM + k0;
        for (int j = 0; j < 8; j++) {
          float4 f = *(const float4*)(src + j * 4);
          tmp[j*4+0] = f2bf(f.x); tmp[j*4+1] = f2bf(f.y);
          tmp[j*4+2] = f2bf(f.z); tmp[j*4+3] = f2bf(f.w);
        }
      } else {
        for (int j = 0; j < 32; j++) tmp[j] = 0;
      }
      for (int j = 0; j < 4; j++)
        *(uint4*)&Bl[tid * 40 + j * 8] = *(uint4*)&tmp[j * 8];
    }
    __syncthreads();
    s16x8 a = *(const s16x8*)&Al[(wave * 16 + l15) * 40 + q * 8];
    for (int ni = 0; ni < 13; ++ni) {
      s16x8 bfr = *(const s16x8*)&Bl[(ni * 16 + l15) * 40 + q * 8];
      acc[ni] = __builtin_amdgcn_mfma_f32_16x16x32_bf16(a, bfr, acc[ni], 0, 0, 0);
    }
    __syncthreads();
  }

  float sq[4] = {0, 0, 0, 0};
  for (int ni = 0; ni < 13; ++ni) {
    const int col = ni * 16 + l15;
    const bool cv = col < HID_DIM;
    const float bias = cv ? Ws_b[col] : 0.f;
    for (int p = 0; p < 4; p++) {
      float v = acc[ni][p] + bias;
      if (cv) sq[p] += v * v;
      const int grow = row0 + wave * 16 + q * 4 + p;
      x_ws[(size_t)grow * HPAD + col] = f2bf(cv ? v : 0.f);
    }
  }
  for (int m = 1; m < 16; m <<= 1)
    for (int p = 0; p < 4; p++) sq[p] += __shfl_xor(sq[p], m, 64);
  if (l15 == 0)
    for (int p = 0; p < 4; p++)
      sumsq_ws[row0 + wave * 16 + q * 4 + p] = sq[p];
}

// ---------------------------------------------------------------------------
// Kernel A2: routing. Emits Ap (A-fragment layout), fp32 poses, expa, D_b.
// ---------------------------------------------------------------------------
__global__ __launch_bounds__(256) void k_routing(
    const int* __restrict__ idx, const int* __restrict__ times,
    const unsigned short* __restrict__ x_ws, const float* __restrict__ sumsq_ws,
    unsigned short* __restrict__ Ap, float* __restrict__ poses_f,
    float* __restrict__ expa_ws, float* __restrict__ D_ws)
{
  __shared__ float u[NN * 201];
  __shared__ float cc[NN];
  __shared__ float bb[NN];
  __shared__ float vv[HID_DIM];
  __shared__ float nrm[NN];
  __shared__ int   sidx[NN];
  __shared__ float red[4];
  __shared__ float scaleS;
  const int tid = threadIdx.x;
  const int b = blockIdx.x;

  if (tid < NN) {
    nrm[tid] = fmaxf(sqrtf(sumsq_ws[b * NN + tid]), 1e-12f);
    sidx[tid] = idx[b * NN + tid];
    bb[tid] = 2.0f / (1.0f + (float)times[b * NN + tid]);
  }
  __syncthreads();
  for (int i = tid; i < NN * HID_DIM; i += 256) {
    const int n = i / HID_DIM, h = i - n * HID_DIM;
    u[n * 201 + h] = bf2f(x_ws[(size_t)(b * NN + n) * HPAD + h]) / nrm[n];
  }
  __syncthreads();

  for (int it = 0; it < 3; ++it) {
    if (tid < 64) {
      float x = (tid < NN) ? bb[tid] : -1e30f;
      float m = x;
      for (int d = 1; d < 64; d <<= 1) m = fmaxf(m, __shfl_xor(m, d, 64));
      float e = (tid < NN) ? __expf(x - m) : 0.f;
      float s = e;
      for (int d = 1; d < 64; d <<= 1) s += __shfl_xor(s, d, 64);
      if (tid < NN) cc[tid] = e * (float)NN / s;
    }
    __syncthreads();
    float sh = 0.f;
    if (tid < HID_DIM)
      for (int n = 0; n < NN; n++) sh += cc[n] * u[n * 201 + tid];
    float sq = (tid < HID_DIM) ? sh * sh : 0.f;
    for (int d = 1; d < 64; d <<= 1) sq += __shfl_xor(sq, d, 64);
    if ((tid & 63) == 0) red[tid >> 6] = sq;
    __syncthreads();
    if (tid == 0) {
      const float t = red[0] + red[1] + red[2] + red[3];
      scaleS = t / (1.0f + t) / sqrtf(t + 1e-9f);
    }
    __syncthreads();
    if (tid < HID_DIM) vv[tid] = scaleS * sh;
    __syncthreads();
    if (it < 2) {
      if (tid < NN) {
        float dot = 0.f;
        for (int h = 0; h < HID_DIM; h++) dot += u[tid * 201 + h] * vv[h];
        bb[tid] += dot;
      }
      __syncthreads();
    }
  }
  // poses scattered into A-fragment layout (zero-padded to KPAD)
  if (tid < KPAD) {
    const float val = (tid < HID_DIM) ? vv[tid] : 0.f;
    const int kt = tid >> 5, rem = tid & 31, q = rem >> 3, j = rem & 7;
    const int mt = b >> 4, l15 = b & 15;
    Ap[(size_t)(((mt * NKT + kt) * 64) + q * 16 + l15) * 8 + j] = f2bf(val);
  }
  if (tid < HID_DIM) poses_f[b * HID_DIM + tid] = vv[tid];
  // dedup of idx within row; D_b = NUM_E + sum_unique (exp(a)-1)
  if (tid < 64) {
    float a = 0.f; int first = 1;
    const int my = (tid < NN) ? sidx[tid] : -1;
    if (tid < NN) {
      for (int n = 0; n < NN; n++)
        if (sidx[n] == my) { a += cc[n]; if (n < tid) first = 0; }
      expa_ws[b * NN + tid] = __expf(a);
    }
    float contrib = (tid < NN && first) ? (__expf(a) - 1.0f) : 0.f;
    for (int d = 1; d < 64; d <<= 1) contrib += __shfl_xor(contrib, d, 64);
    if (tid == 0) D_ws[b] = (float)NUM_E + contrib;
  }
}

// ---------------------------------------------------------------------------
// Kernel P: pre-pack mlp_w into bf16 B-fragment layout, N padded to 50176.
// Bp[((nt*7+kt)*64 + lane)*8 + j]: n = nt*16+l15, k = kt*32+(lane>>4)*8+j
// ---------------------------------------------------------------------------
__global__ __launch_bounds__(256) void k_pack(
    const float* __restrict__ mlp_w, unsigned short* __restrict__ Bp)
{
  const int t = blockIdx.x * 256 + threadIdx.x;
  if (t >= NTT2 * NKT * 64) return;
  const int lane = t & 63;
  const int f = t >> 6;
  const int kt = f % NKT;
  const int nt = f / NKT;
  const int n = nt * 16 + (lane & 15);
  const int kb = kt * 32 + (lane >> 4) * 8;
  unsigned short tmp[8] __attribute__((aligned(16)));
  if (n < NUM_E && kb < HID_DIM) {
    const float* src = mlp_w + (size_t)n * HID_DIM + kb;
    float4 f0 = *(const float4*)(src);
    float4 f1 = *(const float4*)(src + 4);
    tmp[0] = f2bf(f0.x); tmp[1] = f2bf(f0.y); tmp[2] = f2bf(f0.z); tmp[3] = f2bf(f0.w);
    tmp[4] = f2bf(f1.x); tmp[5] = f2bf(f1.y); tmp[6] = f2bf(f1.z); tmp[7] = f2bf(f1.w);
  } else {
    for (int j = 0; j < 8; j++) tmp[j] = 0;
  }
  *(uint4*)&Bp[(size_t)t * 8] = *(uint4*)tmp;
}

// ---------------------------------------------------------------------------
// Kernel G: m97-style GEMM, block tile 64M x 256N, K=224.
// A-tile (28 KB) staged once via global_load_lds; B-tile (16 KB) staged per kt.
// PASS 0: S_b += sum exp(score) (block-reduced, 64 atomics/block).
// PASS 1: out = log(0.5/D + 0.5*exp(score)/S), fp32 coalesced stores.
// ---------------------------------------------------------------------------
template<int PASS>
__global__ __launch_bounds__(256, 3) void k_gemm(
    const unsigned short* __restrict__ Ap, const unsigned short* __restrict__ Bp,
    const float* __restrict__ mlp_b, const float* __restrict__ D_ws,
    float* __restrict__ S_ws, float* __restrict__ out)
{
  __shared__ __align__(16) unsigned short As[28 * 512];  // 28 KB
  __shared__ __align__(16) unsigned short Bs[16 * 512];  // 16 KB
  __shared__ float red[256];
  const int tid = threadIdx.x;
  const int w = tid >> 6, lane = tid & 63;
  const int q = lane >> 4, l15 = lane & 15;
  const int mt0 = blockIdx.y * 4;
  const int m0 = blockIdx.y * 64;
  const int ntb = blockIdx.x * 16 + w * 4;   // wave's first nt tile

  // stage whole A-tile (contiguous 28 KB slice of Ap), 7 chunks per wave
  #pragma unroll
  for (int i = 0; i < 7; ++i) {
    const int c = w * 7 + i;
    gl_lds16(Ap + ((size_t)mt0 * NKT + c) * 512 + lane * 8, &As[c * 512]);
  }
  if (PASS == 1 && tid < 64) {
    red[tid]      = 0.5f / D_ws[m0 + tid];
    red[64 + tid] = 0.5f / S_ws[m0 + tid];
  }
  float bias[4];
  #pragma unroll
  for (int nl = 0; nl < 4; ++nl) {
    const int col = (ntb + nl) * 16 + l15;
    bias[nl] = (col < NUM_E) ? mlp_b[col] : 0.f;
  }

  f32x4 acc[4][4];
  #pragma unroll
  for (int i = 0; i < 4; i++)
    #pragma unroll
    for (int j = 0; j < 4; j++) acc[i][j] = (f32x4){0, 0, 0, 0};

  for (int kt = 0; kt < NKT; ++kt) {
    #pragma unroll
    for (int nl = 0; nl < 4; ++nl)
      gl_lds16(Bp + ((size_t)(ntb + nl) * NKT + kt) * 512 + lane * 8,
               &Bs[(w * 4 + nl) * 512]);
    __syncthreads();   // drains global_load_lds (compiler emits vmcnt(0))
    s16x8 a[4], bfr[4];
    #pragma unroll
    for (int mi = 0; mi < 4; ++mi)
      a[mi] = *(const s16x8*)&As[((mi * NKT + kt) * 64 + lane) * 8];
    #pragma unroll
    for (int nl = 0; nl < 4; ++nl)
      bfr[nl] = *(const s16x8*)&Bs[((w * 4 + nl) * 64 + lane) * 8];
    #pragma unroll
    for (int nl = 0; nl < 4; ++nl)
      #pragma unroll
      for (int mi = 0; mi < 4; ++mi)
        acc[mi][nl] = __builtin_amdgcn_mfma_f32_16x16x32_bf16(a[mi], bfr[nl], acc[mi][nl], 0, 0, 0);
    __syncthreads();   // all waves done reading Bs before next staging
  }

  if (PASS == 0) {
    float rs[4][4];
    #pragma unroll
    for (int mi = 0; mi < 4; mi++)
      #pragma unroll
      for (int p = 0; p < 4; p++) rs[mi][p] = 0.f;
    #pragma unroll
    for (int mi = 0; mi < 4; ++mi)
      #pragma unroll
      for (int nl = 0; nl < 4; ++nl) {
        const int col = (ntb + nl) * 16 + l15;
        #pragma unroll
        for (int p = 0; p < 4; p++) {
          const float v = acc[mi][nl][p] + bias[nl];
          rs[mi][p] += (col < NUM_E) ? __expf(v) : 0.f;
        }
      }
    #pragma unroll
    for (int m = 1; m < 16; m <<= 1)
      for (int mi = 0; mi < 4; mi++)
        for (int p = 0; p < 4; p++)
          rs[mi][p] += __shfl_xor(rs[mi][p], m, 64);
    if (l15 == 0)
      for (int mi = 0; mi < 4; mi++)
        for (int p = 0; p < 4; p++)
          red[w * 64 + mi * 16 + q * 4 + p] = rs[mi][p];
    __syncthreads();
    if (tid < 64)
      atomicAdd(&S_ws[m0 + tid],
                red[tid] + red[64 + tid] + red[128 + tid] + red[192 + tid]);
  } else {
    #pragma unroll
    for (int mi = 0; mi < 4; ++mi) {
      #pragma unroll
      for (int p = 0; p < 4; p++) {
        const int rl = mi * 16 + q * 4 + p;
        const float invD = red[rl];
        const float invS = red[64 + rl];
        const int row = m0 + rl;
        #pragma unroll
        for (int nl = 0; nl < 4; ++nl) {
          const int col = (ntb + nl) * 16 + l15;
          if (col < NUM_E) {
            const float v = acc[mi][nl][p] + bias[nl];
            out[(size_t)row * NUM_E + col] = __logf(fmaf(__expf(v), invS, invD));
          }
        }
      }
    }
  }
}

// ---------------------------------------------------------------------------
// Kernel D: fixup history positions; recompute score via fp32 dot product.
// One wave per (b, slot). Duplicate idx -> identical values, benign race.
// ---------------------------------------------------------------------------
__global__ __launch_bounds__(256) void k_fix(
    const int* __restrict__ idx, const float* __restrict__ expa,
    const float* __restrict__ poses_f, const float* __restrict__ mlp_w,
    const float* __restrict__ mlp_b, const float* __restrict__ D_ws,
    const float* __restrict__ S_ws, float* __restrict__ out)
{
  const int t = blockIdx.x * 4 + (threadIdx.x >> 6);
  const int lane = threadIdx.x & 63;
  if (t >= BATCH * NN) return;
  const int b = t / NN;
  const int j = idx[t];
  float dot = 0.f;
  for (int h = lane; h < HID_DIM; h += 64)
    dot += poses_f[b * HID_DIM + h] * mlp_w[(size_t)j * HID_DIM + h];
  for (int m = 1; m < 64; m <<= 1) dot += __shfl_xor(dot, m, 64);
  if (lane == 0) {
    const float s = dot + mlp_b[j];
    out[(size_t)b * NUM_E + j] = __logf(0.5f * expa[t] / D_ws[b] +
                                        0.5f * __expf(s) / S_ws[b]);
  }
}

extern "C" void kernel_launch(void* const* d_in, const int* in_sizes, int n_in,
                              void* d_out, int out_size, void* d_ws, size_t ws_size,
                              hipStream_t stream) {
  const int*   idx   = (const int*)d_in[0];
  const int*   times = (const int*)d_in[1];
  const float* emb   = (const float*)d_in[2];
  const float* Ws_w  = (const float*)d_in[3];
  const float* Ws_b  = (const float*)d_in[4];
  const float* mlp_w = (const float*)d_in[5];
  const float* mlp_b = (const float*)d_in[6];
  float* out = (float*)d_out;

  char* ws = (char*)d_ws;
  unsigned short* Bp    = (unsigned short*)ws; ws += (size_t)NTT2 * NKT * 64 * 8 * 2;  // 22.5 MB
  unsigned short* x_ws  = (unsigned short*)ws; ws += (size_t)BATCH * NN * HPAD * 2;    // 10.65 MB
  unsigned short* Ap    = (unsigned short*)ws; ws += (size_t)32 * NKT * 64 * 8 * 2;    // 229 KB
  float* poses_f        = (float*)ws;          ws += (size_t)BATCH * HID_DIM * 4;      // 410 KB
  float* sumsq          = (float*)ws;          ws += (size_t)BATCH * NN * 4;           // 102 KB
  float* expa           = (float*)ws;          ws += (size_t)BATCH * NN * 4;           // 102 KB
  float* D_ws           = (float*)ws;          ws += (size_t)BATCH * 4;
  float* S_ws           = (float*)ws;          ws += (size_t)BATCH * 4;

  hipMemsetAsync(S_ws, 0, BATCH * sizeof(float), stream);
  k_pack   <<<dim3((NTT2 * NKT * 64) / 256), 256, 0, stream>>>(mlp_w, Bp);
  k_xgemm  <<<dim3(400),          256, 0, stream>>>(idx, emb, Ws_w, Ws_b, x_ws, sumsq);
  k_routing<<<dim3(BATCH),        256, 0, stream>>>(idx, times, x_ws, sumsq, Ap, poses_f, expa, D_ws);
  k_gemm<0><<<dim3(NXB, 8),       256, 0, stream>>>(Ap, Bp, mlp_b, D_ws, S_ws, out);
  k_gemm<1><<<dim3(NXB, 8),       256, 0, stream>>>(Ap, Bp, mlp_b, D_ws, S_ws, out);
  k_fix    <<<dim3(BATCH * NN / 4), 256, 0, stream>>>(idx, expa, poses_f, mlp_w, mlp_b, D_ws, S_ws, out);
}